// Round 2
// baseline (574.227 us; speedup 1.0000x reference)
//
#include <hip/hip_runtime.h>
#include <hip/hip_bf16.h>

#define S_LEN 2048
#define HID   4096
#define NH    32
#define NKV   8
#define HD    128
#define QKV_N 6144
#define KDIM  4096

typedef __attribute__((ext_vector_type(8))) short short8;
typedef __attribute__((ext_vector_type(4))) float floatx4;
typedef unsigned short ushort;

__device__ __forceinline__ unsigned short f2bu(float f) {
  __hip_bfloat16 b = __float2bfloat16(f);
  return *reinterpret_cast<unsigned short*>(&b);
}
__device__ __forceinline__ void store_c(float* p, float v) { *p = v; }
__device__ __forceinline__ void store_c(__hip_bfloat16* p, float v) { *p = __float2bfloat16(v); }

__device__ __forceinline__ void async_copy16(const void* g, void* l) {
  __builtin_amdgcn_global_load_lds((const __attribute__((address_space(1))) void*)g,
                                   (__attribute__((address_space(3))) void*)l, 16, 0, 0);
}

// ---------------- fp32 -> bf16 convert ----------------
struct bf16x4 { __hip_bfloat16 a, b, c, d; };
__global__ void cvt_f32_bf16(const float* __restrict__ src, __hip_bfloat16* __restrict__ dst, int n4) {
  int i = blockIdx.x * blockDim.x + threadIdx.x;
  if (i < n4) {
    float4 v = ((const float4*)src)[i];
    bf16x4 o = { __float2bfloat16(v.x), __float2bfloat16(v.y),
                 __float2bfloat16(v.z), __float2bfloat16(v.w) };
    ((bf16x4*)dst)[i] = o;
  }
}

// ---------------- NT bf16 GEMM, BK=64, swizzled LDS, global_load_lds staging ----------------
// C[M][N] = sum_k A[m][k]*B[n][k].  LDS[row][chunk c] holds global chunk c^(row&7) (chunk=8 shorts).
template <typename CT>
__global__ __launch_bounds__(256, 2) void gemm_nt(const __hip_bfloat16* __restrict__ A,
                                                  const __hip_bfloat16* __restrict__ B,
                                                  CT* __restrict__ C, int M, int N, int K) {
  __shared__ __align__(16) ushort As[128 * 64];
  __shared__ __align__(16) ushort Bs[128 * 64];
  const int tid  = threadIdx.x;
  const int bm   = blockIdx.y * 128;
  const int bn   = blockIdx.x * 128;
  const int wave = tid >> 6;
  const int lane = tid & 63;
  const int ww   = (wave >> 1) * 64;
  const int wc   = (wave & 1) * 64;
  const int l15  = lane & 15;
  const int quad = lane >> 4;

  const ushort* Au = (const ushort*)A;
  const ushort* Bu = (const ushort*)B;

  // staging: wave stages rows [wave*32, wave*32+32) of each tile, 4 issues x 8 rows x 128B.
  const int rr  = lane >> 3;          // 0..7 row within issue
  const int cc  = lane & 7;           // LDS chunk
  const int gch = cc ^ rr;            // global chunk (rows per issue start at multiple of 8)
  const ushort* Ag = Au + (size_t)(bm + wave * 32 + rr) * K + gch * 8;
  const ushort* Bg = Bu + (size_t)(bn + wave * 32 + rr) * K + gch * 8;

  floatx4 acc[4][4] = {};

  for (int k0 = 0; k0 < K; k0 += 64) {
    __syncthreads();
#pragma unroll
    for (int e = 0; e < 4; ++e) {
      async_copy16(Ag + (size_t)(e * 8) * K + k0, &As[(wave * 32 + e * 8) * 64]);
      async_copy16(Bg + (size_t)(e * 8) * K + k0, &Bs[(wave * 32 + e * 8) * 64]);
    }
    __syncthreads();
#pragma unroll
    for (int kd = 0; kd < 2; ++kd) {
      short8 af[4], bf[4];
#pragma unroll
      for (int i = 0; i < 4; ++i) {
        af[i] = *(const short8*)&As[(ww + i * 16 + l15) * 64 + ((kd * 4 + quad) ^ (l15 & 7)) * 8];
        bf[i] = *(const short8*)&Bs[(wc + i * 16 + l15) * 64 + ((kd * 4 + quad) ^ (l15 & 7)) * 8];
      }
#pragma unroll
      for (int mi = 0; mi < 4; ++mi)
#pragma unroll
        for (int ni = 0; ni < 4; ++ni)
          acc[mi][ni] = __builtin_amdgcn_mfma_f32_16x16x32_bf16(af[mi], bf[ni], acc[mi][ni], 0, 0, 0);
    }
  }
#pragma unroll
  for (int mi = 0; mi < 4; ++mi)
#pragma unroll
    for (int ni = 0; ni < 4; ++ni)
#pragma unroll
      for (int r = 0; r < 4; ++r) {
        int row = bm + ww + mi * 16 + quad * 4 + r;
        int col = bn + wc + ni * 16 + l15;
        store_c(&C[(size_t)row * N + col], acc[mi][ni][r]);
      }
}

// ---------------- RoPE for q,k -> head-major layouts (Q pre-scaled by 1/sqrt(HD)) ----------------
__global__ void rope_qk(const __hip_bfloat16* __restrict__ QKV,
                        const float* __restrict__ cosp, const float* __restrict__ sinp,
                        __hip_bfloat16* __restrict__ Qh, __hip_bfloat16* __restrict__ Kh) {
  int s = blockIdx.y;
  int col = blockIdx.x * 256 + threadIdx.x;
  if (col >= 5120) return;
  const size_t base = (size_t)s * QKV_N;
  float x = __bfloat162float(QKV[base + col]);
  int dd = col & 127;
  float val;
  if (dd < 64) {
    float xp = __bfloat162float(QKV[base + col + 64]);
    val = x * cosp[s * 64 + dd] - xp * sinp[s * 64 + dd];
  } else {
    int f = dd - 64;
    float xp = __bfloat162float(QKV[base + col - 64]);
    val = x * cosp[s * 64 + f] + xp * sinp[s * 64 + f];
  }
  if (col < HID) {
    int h = col >> 7;
    Qh[((size_t)h * S_LEN + s) * HD + dd] = __float2bfloat16(val * 0.08838834764831845f);
  } else {
    int h = (col - HID) >> 7;
    Kh[((size_t)h * S_LEN + s) * HD + dd] = __float2bfloat16(val);
  }
}

// ---------------- V transpose: QKV[s][5120+h*128+d] -> Vt[h][d][s] ----------------
__global__ void v_transpose(const __hip_bfloat16* __restrict__ QKV, __hip_bfloat16* __restrict__ Vt) {
  __shared__ ushort tile[64][130];
  int h = blockIdx.y;
  int s0 = blockIdx.x * 64;
  int t = threadIdx.x;
  const ushort* src = (const ushort*)QKV;
#pragma unroll
  for (int i = 0; i < 32; ++i) {
    int flat = i * 256 + t;
    int r = flat >> 7, c = flat & 127;
    tile[r][c] = src[(size_t)(s0 + r) * QKV_N + 5120 + h * 128 + c];
  }
  __syncthreads();
  ushort* dst = (ushort*)Vt;
#pragma unroll
  for (int i = 0; i < 8; ++i) {
    int g = i * 256 + t;
    int d = g >> 4, j4 = (g & 15) * 4;
    ushort4 o;
    o.x = tile[j4][d]; o.y = tile[j4 + 1][d]; o.z = tile[j4 + 2][d]; o.w = tile[j4 + 3][d];
    *(ushort4*)&dst[((size_t)h * HD + d) * S_LEN + s0 + j4] = o;
  }
}

// ---------------- flash attention v5 ----------------
// 64-row q-tiles (16 rows/wave); each block runs the balanced pair {31-tp, tp} of the
// SAME head sequentially -> every block is exactly 33 K-steps: sustained 2-block/CU
// overlap, no solo-heavy tail.  Swapped QK^T; per-lane partial lsum (reduced once in
// epilogue); speculative exp with old running max (recompute only when defer-max fires).
__global__ __launch_bounds__(256, 2) void attn(const __hip_bfloat16* __restrict__ Qh,
                                               const __hip_bfloat16* __restrict__ Kh,
                                               const __hip_bfloat16* __restrict__ Vt,
                                               __hip_bfloat16* __restrict__ AO) {
  // Ks[b][row][chunk c of 8 shorts] holds K global chunk c^(row&15)
  __shared__ __align__(16) ushort Ks[2][64][128];
  __shared__ __align__(16) ushort P[4][16][72];   // [wave][q 0..15][k 0..63 +pad], stride 144B
  const int bi   = blockIdx.x;                    // 0..511
  const int head = bi & 31;
  const int tp   = bi >> 5;                       // 0..15 -> tile pair {31-tp, tp}
  const int wave = threadIdx.x >> 6;
  const int lane = threadIdx.x & 63;
  const int l15 = lane & 15, quad = lane >> 4;
  const int hk = head & 7;
  const ushort* Qu = (const ushort*)Qh + (size_t)head * S_LEN * HD;
  const ushort* Ku = (const ushort*)Kh + (size_t)hk * S_LEN * HD;
  const ushort* Vu = (const ushort*)Vt + (size_t)hk * HD * S_LEN;

  // staging constants: wave stages rows [wave*16, wave*16+16), 4 issues x 4 rows x 256B
  const int rr4  = lane >> 4;                     // 0..3 row within issue
  const int cc16 = lane & 15;                     // LDS chunk

  auto stage = [&](int b, int j0) {
#pragma unroll
    for (int e = 0; e < 4; ++e) {
      int rt = e * 4 + rr4;                        // 0..15 within wave's 16 rows
      int gc = cc16 ^ rt;                          // global chunk ((wave*16)%16==0)
      async_copy16(Ku + (size_t)(j0 + wave * 16 + rt) * HD + gc * 8,
                   &Ks[b][wave * 16 + e * 4][0]);
    }
  };

  int gpar = 0;          // global step parity across both tiles
  stage(0, 0);

  for (int ti = 0; ti < 2; ++ti) {
    const int t = ti ? tp : (31 - tp);             // heavy tile first
    const bool more = (ti == 0);
    const int q0 = t * 64 + wave * 16;             // wave's 16 q rows

    short8 qf[4];
#pragma unroll
    for (int kd = 0; kd < 4; ++kd)
      qf[kd] = *(const short8*)(Qu + (size_t)(q0 + l15) * HD + kd * 32 + quad * 8);

    floatx4 o[8] = {};
    float mst = -1e30f, lsum = 0.f;                // lsum = per-lane partial (own 16 k's)
    const int nsteps = t + 1;

    for (int s = 0; s < nsteps; ++s) {
      const int j0 = s * 64;
      __syncthreads();
      if (s + 1 < nsteps)      stage((gpar + 1) & 1, (s + 1) * 64);
      else if (more)           stage((gpar + 1) & 1, 0);   // prefetch next tile's first block
      const int b = gpar & 1;
      ++gpar;

      // first-half V loads early: L2 latency hides under QK^T
      short8 vf0[8];
#pragma unroll
      for (int t8 = 0; t8 < 8; ++t8)
        vf0[t8] = *(const short8*)(Vu + (size_t)(t8 * 16 + l15) * S_LEN + j0 + quad * 8);

      // swapped QK^T from swizzled LDS: sc[nt] row = k (quad*4+r), col = q (l15)
      floatx4 sc[4] = {};
      __builtin_amdgcn_s_setprio(1);
#pragma unroll
      for (int nt = 0; nt < 4; ++nt) {
        short8 kf[4];
#pragma unroll
        for (int kd = 0; kd < 4; ++kd)
          kf[kd] = *(const short8*)&Ks[b][nt * 16 + l15][((kd * 4 + quad) ^ l15) * 8];
#pragma unroll
        for (int kd = 0; kd < 4; ++kd)
          sc[nt] = __builtin_amdgcn_mfma_f32_16x16x32_bf16(kf[kd], qf[kd], sc[nt], 0, 0, 0);
      }
      __builtin_amdgcn_s_setprio(0);

      // second-half V loads: latency hides under softmax
      short8 vf1[8];
#pragma unroll
      for (int t8 = 0; t8 < 8; ++t8)
        vf1[t8] = *(const short8*)(Vu + (size_t)(t8 * 16 + l15) * S_LEN + j0 + 32 + quad * 8);

      // softmax for q-row l15 (lane holds k = nt*16+quad*4+r)
      const bool diag = (s == t);
      float pv[16];
      float vmloc = -1e30f;
#pragma unroll
      for (int nt = 0; nt < 4; ++nt)
#pragma unroll
        for (int r = 0; r < 4; ++r) {
          float x = sc[nt][r];
          if (diag && (nt * 16 + quad * 4 + r > wave * 16 + l15)) x = -1e30f;
          pv[nt * 4 + r] = x;
          vmloc = fmaxf(vmloc, x);
        }
      // cross-quad max reduce in flight while speculative exp runs below
      float vm = fmaxf(vmloc, __shfl_xor(vmloc, 16));
      vm = fmaxf(vm, __shfl_xor(vm, 32));
      float ps = 0.f;
      ushort pk[16];
#pragma unroll
      for (int i = 0; i < 16; ++i) {               // speculative: old running max
        float p = __expf(pv[i] - mst);
        ps += p;
        pk[i] = f2bu(p);
      }
      if (__any(vm > mst + 8.0f)) {                // defer-max: rare after first step
        const float mnew = fmaxf(mst, vm);
        const float al = __expf(mst - mnew);
        mst = mnew;
        lsum *= al;
        ps = 0.f;
#pragma unroll
        for (int i = 0; i < 16; ++i) {
          float p = __expf(pv[i] - mst);
          ps += p;
          pk[i] = f2bu(p);
        }
        float ar[4];
#pragma unroll
        for (int r = 0; r < 4; ++r)
          ar[r] = __shfl(al, (lane & 48) | (quad * 4 + r));
#pragma unroll
        for (int t8 = 0; t8 < 8; ++t8)
#pragma unroll
          for (int r = 0; r < 4; ++r) o[t8][r] *= ar[r];
      }
      lsum += ps;                                   // per-lane partial; no shuffles
#pragma unroll
      for (int nt = 0; nt < 4; ++nt) {
        ushort4 w;
        w.x = pk[nt * 4 + 0]; w.y = pk[nt * 4 + 1];
        w.z = pk[nt * 4 + 2]; w.w = pk[nt * 4 + 3];
        *(ushort4*)&P[wave][l15][nt * 16 + quad * 4] = w;
      }

      asm volatile("s_waitcnt lgkmcnt(0)" ::: "memory");
      short8 pf0 = *(const short8*)&P[wave][l15][quad * 8];
      short8 pf1 = *(const short8*)&P[wave][l15][32 + quad * 8];
      __builtin_amdgcn_s_setprio(1);
#pragma unroll
      for (int t8 = 0; t8 < 8; ++t8)
        o[t8] = __builtin_amdgcn_mfma_f32_16x16x32_bf16(pf0, vf0[t8], o[t8], 0, 0, 0);
#pragma unroll
      for (int t8 = 0; t8 < 8; ++t8)
        o[t8] = __builtin_amdgcn_mfma_f32_16x16x32_bf16(pf1, vf1[t8], o[t8], 0, 0, 0);
      __builtin_amdgcn_s_setprio(0);
    }

    // epilogue: reduce lsum across quads once, normalize, store
    lsum += __shfl_xor(lsum, 16);
    lsum += __shfl_xor(lsum, 32);
    float inv[4];
#pragma unroll
    for (int r = 0; r < 4; ++r)
      inv[r] = 1.0f / __shfl(lsum, (lane & 48) | (quad * 4 + r));
#pragma unroll
    for (int r = 0; r < 4; ++r) {
      const int row = q0 + quad * 4 + r;
#pragma unroll
      for (int t8 = 0; t8 < 8; ++t8)
        AO[(size_t)row * HID + head * HD + t8 * 16 + l15] = __float2bfloat16(o[t8][r] * inv[r]);
    }
  }
}

extern "C" void kernel_launch(void* const* d_in, const int* in_sizes, int n_in,
                              void* d_out, int out_size, void* d_ws, size_t ws_size,
                              hipStream_t stream) {
  const float* x    = (const float*)d_in[0];
  const float* wq   = (const float*)d_in[1];
  const float* wk   = (const float*)d_in[2];
  const float* wv   = (const float*)d_in[3];
  const float* wo   = (const float*)d_in[4];
  const float* cosp = (const float*)d_in[5];
  const float* sinp = (const float*)d_in[6];
  float* out = (float*)d_out;

  char* ws = (char*)d_ws;
  size_t off = 0;
  auto alloc = [&](size_t bytes) { char* p = ws + off; off += (bytes + 255) & ~255ull; return p; };
  __hip_bfloat16* Xb   = (__hip_bfloat16*)alloc((size_t)S_LEN * KDIM * 2);
  __hip_bfloat16* Wqkv = (__hip_bfloat16*)alloc((size_t)QKV_N * KDIM * 2);
  __hip_bfloat16* Wob  = (__hip_bfloat16*)alloc((size_t)HID * HID * 2);
  __hip_bfloat16* QKVb = (__hip_bfloat16*)alloc((size_t)S_LEN * QKV_N * 2);
  __hip_bfloat16* Qh   = (__hip_bfloat16*)alloc((size_t)NH * S_LEN * HD * 2);
  __hip_bfloat16* Kh   = (__hip_bfloat16*)alloc((size_t)NKV * S_LEN * HD * 2);
  __hip_bfloat16* Vt   = (__hip_bfloat16*)alloc((size_t)NKV * HD * S_LEN * 2);
  __hip_bfloat16* AO   = (__hip_bfloat16*)alloc((size_t)S_LEN * HID * 2);

  auto cvt = [&](const float* s, __hip_bfloat16* dpt, size_t n) {
    int n4 = (int)(n / 4);
    cvt_f32_bf16<<<dim3((n4 + 255) / 256), dim3(256), 0, stream>>>(s, dpt, n4);
  };
  cvt(x, Xb, (size_t)S_LEN * KDIM);
  cvt(wq, Wqkv, (size_t)HID * KDIM);
  cvt(wk, Wqkv + (size_t)HID * KDIM, (size_t)NKV * HD * KDIM);
  cvt(wv, Wqkv + (size_t)(HID + NKV * HD) * KDIM, (size_t)NKV * HD * KDIM);
  cvt(wo, Wob, (size_t)HID * HID);

  gemm_nt<__hip_bfloat16><<<dim3(QKV_N / 128, S_LEN / 128), dim3(256), 0, stream>>>(
      Xb, Wqkv, QKVb, S_LEN, QKV_N, KDIM);
  rope_qk<<<dim3(20, S_LEN), dim3(256), 0, stream>>>(QKVb, cosp, sinp, Qh, Kh);
  v_transpose<<<dim3(S_LEN / 64, NKV), dim3(256), 0, stream>>>(QKVb, Vt);
  attn<<<dim3(512), dim3(256), 0, stream>>>(Qh, Kh, Vt, AO);
  gemm_nt<float><<<dim3(HID / 128, S_LEN / 128), dim3(256), 0, stream>>>(
      AO, Wob, out, S_LEN, HID, KDIM);
}

// Round 3
// 529.677 us; speedup vs baseline: 1.0841x; 1.0841x over previous
//
#include <hip/hip_runtime.h>
#include <hip/hip_bf16.h>

#define S_LEN 2048
#define HID   4096
#define NH    32
#define NKV   8
#define HD    128
#define QKV_N 6144
#define KDIM  4096

typedef __attribute__((ext_vector_type(8))) short short8;
typedef __attribute__((ext_vector_type(4))) float floatx4;
typedef unsigned short ushort;

__device__ __forceinline__ unsigned short f2bu(float f) {
  __hip_bfloat16 b = __float2bfloat16(f);
  return *reinterpret_cast<unsigned short*>(&b);
}
__device__ __forceinline__ void store_c(float* p, float v) { *p = v; }
__device__ __forceinline__ void store_c(__hip_bfloat16* p, float v) { *p = __float2bfloat16(v); }

__device__ __forceinline__ void async_copy16(const void* g, void* l) {
  __builtin_amdgcn_global_load_lds((const __attribute__((address_space(1))) void*)g,
                                   (__attribute__((address_space(3))) void*)l, 16, 0, 0);
}

// ---------------- fp32 -> bf16 convert ----------------
struct bf16x4 { __hip_bfloat16 a, b, c, d; };
__global__ void cvt_f32_bf16(const float* __restrict__ src, __hip_bfloat16* __restrict__ dst, int n4) {
  int i = blockIdx.x * blockDim.x + threadIdx.x;
  if (i < n4) {
    float4 v = ((const float4*)src)[i];
    bf16x4 o = { __float2bfloat16(v.x), __float2bfloat16(v.y),
                 __float2bfloat16(v.z), __float2bfloat16(v.w) };
    ((bf16x4*)dst)[i] = o;
  }
}

// ---------------- NT bf16 GEMM, BK=64, swizzled LDS, global_load_lds staging ----------------
// C[M][N] = sum_k A[m][k]*B[n][k].  LDS[row][chunk c] holds global chunk c^(row&7) (chunk=8 shorts).
template <typename CT>
__global__ __launch_bounds__(256, 2) void gemm_nt(const __hip_bfloat16* __restrict__ A,
                                                  const __hip_bfloat16* __restrict__ B,
                                                  CT* __restrict__ C, int M, int N, int K) {
  __shared__ __align__(16) ushort As[128 * 64];
  __shared__ __align__(16) ushort Bs[128 * 64];
  const int tid  = threadIdx.x;
  const int bm   = blockIdx.y * 128;
  const int bn   = blockIdx.x * 128;
  const int wave = tid >> 6;
  const int lane = tid & 63;
  const int ww   = (wave >> 1) * 64;
  const int wc   = (wave & 1) * 64;
  const int l15  = lane & 15;
  const int quad = lane >> 4;

  const ushort* Au = (const ushort*)A;
  const ushort* Bu = (const ushort*)B;

  // staging: wave stages rows [wave*32, wave*32+32) of each tile, 4 issues x 8 rows x 128B.
  const int rr  = lane >> 3;          // 0..7 row within issue
  const int cc  = lane & 7;           // LDS chunk
  const int gch = cc ^ rr;            // global chunk (rows per issue start at multiple of 8)
  const ushort* Ag = Au + (size_t)(bm + wave * 32 + rr) * K + gch * 8;
  const ushort* Bg = Bu + (size_t)(bn + wave * 32 + rr) * K + gch * 8;

  floatx4 acc[4][4] = {};

  for (int k0 = 0; k0 < K; k0 += 64) {
    __syncthreads();
#pragma unroll
    for (int e = 0; e < 4; ++e) {
      async_copy16(Ag + (size_t)(e * 8) * K + k0, &As[(wave * 32 + e * 8) * 64]);
      async_copy16(Bg + (size_t)(e * 8) * K + k0, &Bs[(wave * 32 + e * 8) * 64]);
    }
    __syncthreads();
#pragma unroll
    for (int kd = 0; kd < 2; ++kd) {
      short8 af[4], bf[4];
#pragma unroll
      for (int i = 0; i < 4; ++i) {
        af[i] = *(const short8*)&As[(ww + i * 16 + l15) * 64 + ((kd * 4 + quad) ^ (l15 & 7)) * 8];
        bf[i] = *(const short8*)&Bs[(wc + i * 16 + l15) * 64 + ((kd * 4 + quad) ^ (l15 & 7)) * 8];
      }
#pragma unroll
      for (int mi = 0; mi < 4; ++mi)
#pragma unroll
        for (int ni = 0; ni < 4; ++ni)
          acc[mi][ni] = __builtin_amdgcn_mfma_f32_16x16x32_bf16(af[mi], bf[ni], acc[mi][ni], 0, 0, 0);
    }
  }
#pragma unroll
  for (int mi = 0; mi < 4; ++mi)
#pragma unroll
    for (int ni = 0; ni < 4; ++ni)
#pragma unroll
      for (int r = 0; r < 4; ++r) {
        int row = bm + ww + mi * 16 + quad * 4 + r;
        int col = bn + wc + ni * 16 + l15;
        store_c(&C[(size_t)row * N + col], acc[mi][ni][r]);
      }
}

// ---------------- RoPE for q,k -> head-major layouts (Q pre-scaled by 1/sqrt(HD)) ----------------
__global__ void rope_qk(const __hip_bfloat16* __restrict__ QKV,
                        const float* __restrict__ cosp, const float* __restrict__ sinp,
                        __hip_bfloat16* __restrict__ Qh, __hip_bfloat16* __restrict__ Kh) {
  int s = blockIdx.y;
  int col = blockIdx.x * 256 + threadIdx.x;
  if (col >= 5120) return;
  const size_t base = (size_t)s * QKV_N;
  float x = __bfloat162float(QKV[base + col]);
  int dd = col & 127;
  float val;
  if (dd < 64) {
    float xp = __bfloat162float(QKV[base + col + 64]);
    val = x * cosp[s * 64 + dd] - xp * sinp[s * 64 + dd];
  } else {
    int f = dd - 64;
    float xp = __bfloat162float(QKV[base + col - 64]);
    val = x * cosp[s * 64 + f] + xp * sinp[s * 64 + f];
  }
  if (col < HID) {
    int h = col >> 7;
    Qh[((size_t)h * S_LEN + s) * HD + dd] = __float2bfloat16(val * 0.08838834764831845f);
  } else {
    int h = (col - HID) >> 7;
    Kh[((size_t)h * S_LEN + s) * HD + dd] = __float2bfloat16(val);
  }
}

// ---------------- V transpose: QKV[s][5120+h*128+d] -> Vt[h][d][s] ----------------
__global__ void v_transpose(const __hip_bfloat16* __restrict__ QKV, __hip_bfloat16* __restrict__ Vt) {
  __shared__ ushort tile[64][130];
  int h = blockIdx.y;
  int s0 = blockIdx.x * 64;
  int t = threadIdx.x;
  const ushort* src = (const ushort*)QKV;
#pragma unroll
  for (int i = 0; i < 32; ++i) {
    int flat = i * 256 + t;
    int r = flat >> 7, c = flat & 127;
    tile[r][c] = src[(size_t)(s0 + r) * QKV_N + 5120 + h * 128 + c];
  }
  __syncthreads();
  ushort* dst = (ushort*)Vt;
#pragma unroll
  for (int i = 0; i < 8; ++i) {
    int g = i * 256 + t;
    int d = g >> 4, j4 = (g & 15) * 4;
    ushort4 o;
    o.x = tile[j4][d]; o.y = tile[j4 + 1][d]; o.z = tile[j4 + 2][d]; o.w = tile[j4 + 3][d];
    *(ushort4*)&dst[((size_t)h * HD + d) * S_LEN + s0 + j4] = o;
  }
}

// ---------------- flash attention v6 ----------------
// 2-wave blocks (128 thr), 64-row tile = 2 x 32 q-rows/wave (v4 amortization).
// 1024 blocks all co-resident at 4 blocks/CU (8 waves/CU, 2/SIMD): the (g,u)->t map
// makes every CU's four resident blocks sum to exactly 66 K-steps -> perfect balance
// with full per-step efficiency.  Single-buffered K, two-barrier split hides staging
// under softmax+PV.  Swapped QK^T, per-lane lsum, speculative exp + defer-max.
__global__ __launch_bounds__(128, 2) void attn(const __hip_bfloat16* __restrict__ Qh,
                                               const __hip_bfloat16* __restrict__ Kh,
                                               const __hip_bfloat16* __restrict__ Vt,
                                               __hip_bfloat16* __restrict__ AO) {
  __shared__ __align__(16) ushort Ks[64][128];    // [row][chunk c] = K chunk c^(row&15)
  __shared__ __align__(16) ushort P[2][32][72];   // [wave][q 0..31][k 0..63 +pad]
  const int bi   = blockIdx.x;                    // 0..1023
  const int g    = bi >> 8;                       // 0..3
  const int c    = bi & 255;
  const int head = c & 31;
  const int u    = c >> 5;                        // 0..7
  const int t    = (g == 0) ? (24 + u) : (g == 1) ? (16 + u)
                 : (g == 2) ? (15 - u) : (7 - u); // per-CU sums = 66 steps for all u
  const int wave = threadIdx.x >> 6;              // 0..1
  const int lane = threadIdx.x & 63;
  const int l15 = lane & 15, quad = lane >> 4;
  const int hk = head & 7;
  const int q0 = t * 64 + wave * 32;              // wave's 32 q rows
  const ushort* Qu = (const ushort*)Qh + (size_t)head * S_LEN * HD;
  const ushort* Ku = (const ushort*)Kh + (size_t)hk * S_LEN * HD;
  const ushort* Vu = (const ushort*)Vt + (size_t)hk * HD * S_LEN;

  // staging: wave stages rows [wave*32, wave*32+32), 8 issues x 4 rows x 256B
  const int rr4  = lane >> 4;                     // row within issue
  const int cc16 = lane & 15;                     // LDS chunk
  auto stage = [&](int j0) {
#pragma unroll
    for (int e = 0; e < 8; ++e) {
      int rt = (e * 4 + rr4) & 15;
      int gc = cc16 ^ rt;
      async_copy16(Ku + (size_t)(j0 + wave * 32 + e * 4 + rr4) * HD + gc * 8,
                   &Ks[wave * 32 + e * 4][0]);
    }
  };

  short8 qf[2][4];
#pragma unroll
  for (int mt = 0; mt < 2; ++mt)
#pragma unroll
    for (int kd = 0; kd < 4; ++kd)
      qf[mt][kd] = *(const short8*)(Qu + (size_t)(q0 + mt * 16 + l15) * HD + kd * 32 + quad * 8);

  floatx4 o[2][8] = {};
  float mst[2], lsum[2];
  mst[0] = mst[1] = -1e30f;
  lsum[0] = lsum[1] = 0.f;
  const int nsteps = t + 1;

  stage(0);
  for (int s = 0; s < nsteps; ++s) {
    const int j0 = s * 64;
    __syncthreads();                              // barrier A: vmcnt drain -> Ks ready

    // swapped QK^T from swizzled LDS: sc[mt][nt] row = k (quad*4+r), col = q (l15)
    floatx4 sc[2][4];
#pragma unroll
    for (int mt = 0; mt < 2; ++mt)
#pragma unroll
      for (int nt = 0; nt < 4; ++nt) sc[mt][nt] = floatx4{0.f, 0.f, 0.f, 0.f};
    __builtin_amdgcn_s_setprio(1);
#pragma unroll
    for (int nt = 0; nt < 4; ++nt) {
      short8 kf[4];
#pragma unroll
      for (int kd = 0; kd < 4; ++kd)
        kf[kd] = *(const short8*)&Ks[nt * 16 + l15][((kd * 4 + quad) ^ l15) * 8];
#pragma unroll
      for (int mt = 0; mt < 2; ++mt)
#pragma unroll
        for (int kd = 0; kd < 4; ++kd)
          sc[mt][nt] = __builtin_amdgcn_mfma_f32_16x16x32_bf16(kf[kd], qf[mt][kd], sc[mt][nt], 0, 0, 0);
    }
    __builtin_amdgcn_s_setprio(0);
    __syncthreads();                              // barrier B: all waves done reading Ks
    if (s + 1 < nsteps) stage(j0 + 64);           // overwrite Ks; latency hides under below

    // first-half V loads: L2 latency hides under softmax
    short8 vf0[8];
#pragma unroll
    for (int t8 = 0; t8 < 8; ++t8)
      vf0[t8] = *(const short8*)(Vu + (size_t)(t8 * 16 + l15) * S_LEN + j0 + quad * 8);

    // softmax per mt for q-row l15 (lane holds k = nt*16+quad*4+r)
    const bool diag = (s == t);
#pragma unroll
    for (int mt = 0; mt < 2; ++mt) {
      const int qloc = wave * 32 + mt * 16 + l15;  // q within tile
      float pv[16];
      float vmloc = -1e30f;
#pragma unroll
      for (int nt = 0; nt < 4; ++nt)
#pragma unroll
        for (int r = 0; r < 4; ++r) {
          float x = sc[mt][nt][r];
          if (diag && (nt * 16 + quad * 4 + r > qloc)) x = -1e30f;
          pv[nt * 4 + r] = x;
          vmloc = fmaxf(vmloc, x);
        }
      float vm = fmaxf(vmloc, __shfl_xor(vmloc, 16));
      vm = fmaxf(vm, __shfl_xor(vm, 32));
      float ps = 0.f;
      ushort pk[16];
#pragma unroll
      for (int i = 0; i < 16; ++i) {               // speculative: old running max
        float p = __expf(pv[i] - mst[mt]);
        ps += p;
        pk[i] = f2bu(p);
      }
      if (__any(vm > mst[mt] + 8.0f)) {            // defer-max: rare after first step
        const float mnew = fmaxf(mst[mt], vm);
        const float al = __expf(mst[mt] - mnew);
        mst[mt] = mnew;
        lsum[mt] *= al;
        ps = 0.f;
#pragma unroll
        for (int i = 0; i < 16; ++i) {
          float p = __expf(pv[i] - mst[mt]);
          ps += p;
          pk[i] = f2bu(p);
        }
        float ar[4];
#pragma unroll
        for (int r = 0; r < 4; ++r)
          ar[r] = __shfl(al, (lane & 48) | (quad * 4 + r));
#pragma unroll
        for (int t8 = 0; t8 < 8; ++t8)
#pragma unroll
          for (int r = 0; r < 4; ++r) o[mt][t8][r] *= ar[r];
      }
      lsum[mt] += ps;                              // per-lane partial; no shuffles
#pragma unroll
      for (int nt = 0; nt < 4; ++nt) {
        ushort4 w;
        w.x = pk[nt * 4 + 0]; w.y = pk[nt * 4 + 1];
        w.z = pk[nt * 4 + 2]; w.w = pk[nt * 4 + 3];
        *(ushort4*)&P[wave][mt * 16 + l15][nt * 16 + quad * 4] = w;
      }
    }

    // second-half V loads
    short8 vf1[8];
#pragma unroll
    for (int t8 = 0; t8 < 8; ++t8)
      vf1[t8] = *(const short8*)(Vu + (size_t)(t8 * 16 + l15) * S_LEN + j0 + 32 + quad * 8);

    asm volatile("s_waitcnt lgkmcnt(0)" ::: "memory");
    short8 pf[2][2];
#pragma unroll
    for (int mt = 0; mt < 2; ++mt)
#pragma unroll
      for (int hh = 0; hh < 2; ++hh)
        pf[mt][hh] = *(const short8*)&P[wave][mt * 16 + l15][hh * 32 + quad * 8];
    __builtin_amdgcn_s_setprio(1);
#pragma unroll
    for (int t8 = 0; t8 < 8; ++t8)
#pragma unroll
      for (int mt = 0; mt < 2; ++mt) {
        o[mt][t8] = __builtin_amdgcn_mfma_f32_16x16x32_bf16(pf[mt][0], vf0[t8], o[mt][t8], 0, 0, 0);
        o[mt][t8] = __builtin_amdgcn_mfma_f32_16x16x32_bf16(pf[mt][1], vf1[t8], o[mt][t8], 0, 0, 0);
      }
    __builtin_amdgcn_s_setprio(0);
  }

  // epilogue: reduce lsum across quads, normalize, store
#pragma unroll
  for (int mt = 0; mt < 2; ++mt) {
    float ls = lsum[mt];
    ls += __shfl_xor(ls, 16);
    ls += __shfl_xor(ls, 32);
    float inv[4];
#pragma unroll
    for (int r = 0; r < 4; ++r)
      inv[r] = 1.0f / __shfl(ls, (lane & 48) | (quad * 4 + r));
#pragma unroll
    for (int r = 0; r < 4; ++r) {
      const int row = q0 + mt * 16 + quad * 4 + r;
#pragma unroll
      for (int t8 = 0; t8 < 8; ++t8)
        AO[(size_t)row * HID + head * HD + t8 * 16 + l15] = __float2bfloat16(o[mt][t8][r] * inv[r]);
    }
  }
}

extern "C" void kernel_launch(void* const* d_in, const int* in_sizes, int n_in,
                              void* d_out, int out_size, void* d_ws, size_t ws_size,
                              hipStream_t stream) {
  const float* x    = (const float*)d_in[0];
  const float* wq   = (const float*)d_in[1];
  const float* wk   = (const float*)d_in[2];
  const float* wv   = (const float*)d_in[3];
  const float* wo   = (const float*)d_in[4];
  const float* cosp = (const float*)d_in[5];
  const float* sinp = (const float*)d_in[6];
  float* out = (float*)d_out;

  char* ws = (char*)d_ws;
  size_t off = 0;
  auto alloc = [&](size_t bytes) { char* p = ws + off; off += (bytes + 255) & ~255ull; return p; };
  __hip_bfloat16* Xb   = (__hip_bfloat16*)alloc((size_t)S_LEN * KDIM * 2);
  __hip_bfloat16* Wqkv = (__hip_bfloat16*)alloc((size_t)QKV_N * KDIM * 2);
  __hip_bfloat16* Wob  = (__hip_bfloat16*)alloc((size_t)HID * HID * 2);
  __hip_bfloat16* QKVb = (__hip_bfloat16*)alloc((size_t)S_LEN * QKV_N * 2);
  __hip_bfloat16* Qh   = (__hip_bfloat16*)alloc((size_t)NH * S_LEN * HD * 2);
  __hip_bfloat16* Kh   = (__hip_bfloat16*)alloc((size_t)NKV * S_LEN * HD * 2);
  __hip_bfloat16* Vt   = (__hip_bfloat16*)alloc((size_t)NKV * HD * S_LEN * 2);
  __hip_bfloat16* AO   = (__hip_bfloat16*)alloc((size_t)S_LEN * HID * 2);

  auto cvt = [&](const float* s, __hip_bfloat16* dpt, size_t n) {
    int n4 = (int)(n / 4);
    cvt_f32_bf16<<<dim3((n4 + 255) / 256), dim3(256), 0, stream>>>(s, dpt, n4);
  };
  cvt(x, Xb, (size_t)S_LEN * KDIM);
  cvt(wq, Wqkv, (size_t)HID * KDIM);
  cvt(wk, Wqkv + (size_t)HID * KDIM, (size_t)NKV * HD * KDIM);
  cvt(wv, Wqkv + (size_t)(HID + NKV * HD) * KDIM, (size_t)NKV * HD * KDIM);
  cvt(wo, Wob, (size_t)HID * HID);

  gemm_nt<__hip_bfloat16><<<dim3(QKV_N / 128, S_LEN / 128), dim3(256), 0, stream>>>(
      Xb, Wqkv, QKVb, S_LEN, QKV_N, KDIM);
  rope_qk<<<dim3(20, S_LEN), dim3(256), 0, stream>>>(QKVb, cosp, sinp, Qh, Kh);
  v_transpose<<<dim3(S_LEN / 64, NKV), dim3(256), 0, stream>>>(QKVb, Vt);
  attn<<<dim3(1024), dim3(128), 0, stream>>>(Qh, Kh, Vt, AO);
  gemm_nt<float><<<dim3(HID / 128, S_LEN / 128), dim3(256), 0, stream>>>(
      AO, Wob, out, S_LEN, HID, KDIM);
}